// Round 4
// baseline (1286.203 us; speedup 1.0000x reference)
//
#include <hip/hip_runtime.h>
#include <hip/hip_bf16.h>

#define EMBED 1024
#define TSEQ  1024
#define NB    16
#define NH    16
#define HD    64
#define MROWS (NB * TSEQ)   // 16384

typedef __bf16 bf16x8 __attribute__((ext_vector_type(8)));
typedef float  f32x4  __attribute__((ext_vector_type(4)));

// float -> bf16 bits, round-to-nearest-even (finite inputs only)
__device__ __forceinline__ unsigned int f2bf_bits(float x) {
    union { float f; unsigned int u; } v; v.f = x;
    unsigned int r = v.u + 0x7FFFu + ((v.u >> 16) & 1u);
    return r >> 16;
}

// async global->LDS, 16 B per lane; LDS dest = wave-uniform base + lane*16
__device__ __forceinline__ void gl2lds16(const void* g, void* lds) {
    __builtin_amdgcn_global_load_lds(
        (const __attribute__((address_space(1))) unsigned int*)g,
        (__attribute__((address_space(3))) unsigned int*)lds, 16, 0, 0);
}

// ---------------------------------------------------------------------------
// Input-dtype sniff (proven R2/R3): bits[14:7] of u32 words of X are the low
// bf16's exponent byte if packed-bf16 (~always in [100,150] for N(0,1)), but
// mid-mantissa bits (~uniform) if f32.
// ---------------------------------------------------------------------------
__device__ __forceinline__ int detect_bf16(const unsigned int* __restrict__ X) {
    __shared__ int s_cnt;
    if (threadIdx.x == 0) s_cnt = 0;
    __syncthreads();
    int c = 0;
    const int base = threadIdx.x * 16;
#pragma unroll
    for (int i = 0; i < 16; ++i) {
        unsigned int e = (X[base + i] >> 7) & 0xFFu;
        c += (e >= 100u && e <= 150u) ? 1 : 0;
    }
    atomicAdd(&s_cnt, c);
    __syncthreads();
    return s_cnt >= 2458;   // 0.6 * 4096
}

__device__ __forceinline__ uint4 load8(const void* __restrict__ p, size_t eoff,
                                       int is_bf16) {
    if (is_bf16) {
        return *(const uint4*)((const __hip_bfloat16*)p + eoff);
    }
    const float* f = (const float*)p + eoff;
    float4 a = *(const float4*)f;
    float4 b = *(const float4*)(f + 4);
    uint4 r;
    r.x = f2bf_bits(a.x) | (f2bf_bits(a.y) << 16);
    r.y = f2bf_bits(a.z) | (f2bf_bits(a.w) << 16);
    r.z = f2bf_bits(b.x) | (f2bf_bits(b.y) << 16);
    r.w = f2bf_bits(b.z) | (f2bf_bits(b.w) << 16);
    return r;
}

// ---------------------------------------------------------------------------
// C[m][n] = sum_k A[m][k] * W[n][k]  (+ bias[n])
// 128x128 tile, BK=32, 256 thr (4 waves), 16x16x32 bf16 MFMA, 4x4/wave.
// Fast path (all-bf16, the measured case): global_load_lds width-16 staging
// into unpadded [128][32] tiles with XOR chunk swizzle slot = c ^ ((row>>1)&3)
// (applied to the SOURCE address; DMA dest is fixed base+lane*16). Frag reads
// land 2-way bank-aliased = free. Flex path (any f32 operand): R3 structure.
// out_mode: 0 = bf16 C; 1 = detected-dtype C; 2 = bf16 Vt[b][h][d][t].
// ---------------------------------------------------------------------------
#define BK  32
#define LDK 40

__global__ __launch_bounds__(256) void gemm_flex(
    const void* __restrict__ A,
    const void* __restrict__ W,
    void* __restrict__ C,
    const void* __restrict__ bias,
    const unsigned int* __restrict__ Xdet,
    int a_flex, int out_mode)
{
    const int isbf = detect_bf16(Xdet);

    __shared__ __hip_bfloat16 As[128 * LDK];   // flex: stride 40; fast: stride 32
    __shared__ __hip_bfloat16 Bs[128 * LDK];

    const int tid  = threadIdx.x;
    const int lane = tid & 63;
    const int w    = tid >> 6;
    const int wm   = w & 1;
    const int wn   = w >> 1;
    const int m0   = blockIdx.x * 128;
    const int n0   = blockIdx.y * 128;

    f32x4 acc[4][4];
#pragma unroll
    for (int i = 0; i < 4; ++i)
#pragma unroll
        for (int j = 0; j < 4; ++j)
            acc[i][j] = (f32x4){0.f, 0.f, 0.f, 0.f};

    const int fr = lane & 15;
    const int fq = lane >> 4;

    if (isbf) {
        // ---- fast path ----
        // staging geometry: flat 16B chunk f = n*256 + w*64 + lane;
        // row = f>>2 (+64 for n=1), slot = f&3, source chunk = slot^((row>>1)&3)
        const int f0   = w * 64 + lane;
        const int row  = f0 >> 2;
        const int slot = f0 & 3;
        const int gch  = slot ^ ((row >> 1) & 3);
        const __hip_bfloat16* gA =
            (const __hip_bfloat16*)A + (size_t)(m0 + row) * EMBED + gch * 8;
        const __hip_bfloat16* gB =
            (const __hip_bfloat16*)W + (size_t)(n0 + row) * EMBED + gch * 8;
        __hip_bfloat16* lA0 = &As[w * 512];          // chunks [w*64, +64)
        __hip_bfloat16* lA1 = &As[2048 + w * 512];   // chunks [256+w*64, +64)
        __hip_bfloat16* lB0 = &Bs[w * 512];
        __hip_bfloat16* lB1 = &Bs[2048 + w * 512];

        // frag-read swizzled slot (lane-constant: rows differ by multiples of 2)
        const int rslot = (fq ^ ((fr >> 1) & 3)) * 8;

        for (int k0 = 0; k0 < EMBED; k0 += BK) {
            __syncthreads();   // prev iter's frag reads done before DMA overwrite
            gl2lds16(gA + k0, lA0);
            gl2lds16(gA + k0 + (size_t)64 * EMBED, lA1);
            gl2lds16(gB + k0, lB0);
            gl2lds16(gB + k0 + (size_t)64 * EMBED, lB1);
            __syncthreads();   // drains vmcnt -> tiles resident

            bf16x8 af[4], bfr[4];
#pragma unroll
            for (int i = 0; i < 4; ++i) {
                af[i]  = *(const bf16x8*)&As[(wm * 64 + i * 16 + fr) * 32 + rslot];
                bfr[i] = *(const bf16x8*)&Bs[(wn * 64 + i * 16 + fr) * 32 + rslot];
            }
#pragma unroll
            for (int i = 0; i < 4; ++i)
#pragma unroll
                for (int j = 0; j < 4; ++j)
                    acc[i][j] = __builtin_amdgcn_mfma_f32_16x16x32_bf16(
                        af[i], bfr[j], acc[i][j], 0, 0, 0);
        }
    } else {
        // ---- flex path (any-f32 operands; R3 structure) ----
        const int a_bf = a_flex ? 0 : 1;   // isbf==0 here
        const int r0 = tid >> 2;
        const int c0 = (tid & 3) * 8;
        for (int k0 = 0; k0 < EMBED; k0 += BK) {
            uint4 ra0 = load8(A, (size_t)(m0 + r0)      * EMBED + c0 + k0, a_bf);
            uint4 ra1 = load8(A, (size_t)(m0 + r0 + 64) * EMBED + c0 + k0, a_bf);
            uint4 rb0 = load8(W, (size_t)(n0 + r0)      * EMBED + c0 + k0, 0);
            uint4 rb1 = load8(W, (size_t)(n0 + r0 + 64) * EMBED + c0 + k0, 0);
            __syncthreads();
            *(uint4*)&As[r0 * LDK + c0]        = ra0;
            *(uint4*)&As[(r0 + 64) * LDK + c0] = ra1;
            *(uint4*)&Bs[r0 * LDK + c0]        = rb0;
            *(uint4*)&Bs[(r0 + 64) * LDK + c0] = rb1;
            __syncthreads();

            bf16x8 af[4], bfr[4];
#pragma unroll
            for (int i = 0; i < 4; ++i) {
                af[i]  = *(const bf16x8*)&As[(wm * 64 + i * 16 + fr) * LDK + fq * 8];
                bfr[i] = *(const bf16x8*)&Bs[(wn * 64 + i * 16 + fr) * LDK + fq * 8];
            }
#pragma unroll
            for (int i = 0; i < 4; ++i)
#pragma unroll
                for (int j = 0; j < 4; ++j)
                    acc[i][j] = __builtin_amdgcn_mfma_f32_16x16x32_bf16(
                        af[i], bfr[j], acc[i][j], 0, 0, 0);
        }
    }

    float bv[4] = {0.f, 0.f, 0.f, 0.f};
    if (bias != nullptr) {
#pragma unroll
        for (int j = 0; j < 4; ++j) {
            const int idx = n0 + wn * 64 + j * 16 + fr;
            bv[j] = isbf ? __bfloat162float(((const __hip_bfloat16*)bias)[idx])
                         : ((const float*)bias)[idx];
        }
    }

    if (out_mode == 2) {
        // Vt[b][h][d][t]: C-layout regs r=0..3 are 4 consecutive t -> uint2
#pragma unroll
        for (int i = 0; i < 4; ++i) {
            const int row = m0 + wm * 64 + i * 16 + fq * 4;   // token (base)
            const int bb = row >> 10, tt = row & 1023;
#pragma unroll
            for (int j = 0; j < 4; ++j) {
                const int col = n0 + wn * 64 + j * 16 + fr;   // channel
                const int hh = col >> 6, dd = col & 63;
                uint2 st;
                st.x = f2bf_bits(acc[i][j][0]) | (f2bf_bits(acc[i][j][1]) << 16);
                st.y = f2bf_bits(acc[i][j][2]) | (f2bf_bits(acc[i][j][3]) << 16);
                *(uint2*)&((__hip_bfloat16*)C)[
                    (((size_t)(bb * NH + hh) * HD + dd) * TSEQ) + tt] = st;
            }
        }
        return;
    }

    const int c_bf = (out_mode == 1) ? isbf : 1;
#pragma unroll
    for (int i = 0; i < 4; ++i) {
        const int row = m0 + wm * 64 + i * 16 + fq * 4;
#pragma unroll
        for (int j = 0; j < 4; ++j) {
            const int col = n0 + wn * 64 + j * 16 + fr;
#pragma unroll
            for (int r = 0; r < 4; ++r) {
                const size_t off = (size_t)(row + r) * EMBED + col;
                const float v = acc[i][j][r] + bv[j];
                if (c_bf) ((__hip_bfloat16*)C)[off] = __float2bfloat16(v);
                else      ((float*)C)[off] = v;
            }
        }
    }
}

// ---------------------------------------------------------------------------
// MFMA flash attention. Block = 256 thr (4 waves) x 128 queries (32 q/wave,
// processed as two 16-q sub-tiles to cap live VGPRs); 8 KV-tiles of 128 keys.
// K/V frag DS reads are q-independent -> 2x amortization vs R3's 16 q/wave.
// Q A-frags in regs; K staged [key][d]; V pre-transposed by the V-GEMM,
// staged [d][key]. P transposes through per-wave LDS. O written over Q.
// ---------------------------------------------------------------------------
#define QT  128
#define KTL 128
#define KP  72    // Ks pitch: [128 keys][64 d + 8 pad]
#define VP  136   // Vs pitch: [64 d][128 keys + 8 pad]
#define PP  136   // Ps pitch: per wave [16 q][128 keys + 8 pad]

__global__ __launch_bounds__(256) void attn_mfma(
    const __hip_bfloat16* __restrict__ Q,
    const __hip_bfloat16* __restrict__ K,
    const __hip_bfloat16* __restrict__ Vt,
    const int* __restrict__ mask,
    __hip_bfloat16* __restrict__ O)
{
    __shared__ __hip_bfloat16 Ks[KTL * KP];
    __shared__ __hip_bfloat16 Vs[HD * VP];
    __shared__ __hip_bfloat16 Ps[4][16 * PP];

    const int tid  = threadIdx.x;
    const int lane = tid & 63;
    const int w    = tid >> 6;
    const int fr   = lane & 15;
    const int fq   = lane >> 4;
    const int qb = blockIdx.x, h = blockIdx.y, b = blockIdx.z;
    const int q0 = qb * QT;

    // Q A-frags for both 16-q sub-tiles: A[m=fr][k=fq*8+j], k-chunks 0/32
    bf16x8 qa[2][2];
#pragma unroll
    for (int qt = 0; qt < 2; ++qt) {
        const __hip_bfloat16* qptr =
            Q + (size_t)(b * TSEQ + q0 + w * 32 + qt * 16 + fr) * EMBED
              + h * HD + fq * 8;
        qa[qt][0] = *(const bf16x8*)qptr;
        qa[qt][1] = *(const bf16x8*)(qptr + 32);
    }

    float mS[2][4], lS[2][4];
    f32x4 oacc[2][4];
#pragma unroll
    for (int qt = 0; qt < 2; ++qt)
#pragma unroll
        for (int r = 0; r < 4; ++r) {
            mS[qt][r] = -1e30f; lS[qt][r] = 0.f;
            oacc[qt][r] = (f32x4){0.f, 0.f, 0.f, 0.f};
        }

    for (int kt = 0; kt < TSEQ / KTL; ++kt) {
        __syncthreads();
        // stage K tile [128 keys][64 d] and Vt tile [64 d][128 keys]
#pragma unroll
        for (int i = 0; i < 4; ++i) {
            const int cc  = tid + 256 * i;        // 0..1023
            const int key = cc >> 3;
            const int dc  = (cc & 7) * 8;
            *(uint4*)&Ks[key * KP + dc] = *(const uint4*)(
                K + (size_t)(b * TSEQ + kt * KTL + key) * EMBED + h * HD + dc);
            const int d  = cc >> 4;
            const int kc = (cc & 15) * 8;
            *(uint4*)&Vs[d * VP + kc] = *(const uint4*)(
                Vt + ((size_t)(b * NH + h) * HD + d) * TSEQ + kt * KTL + kc);
        }
        __syncthreads();

#pragma unroll 1
        for (int qt = 0; qt < 2; ++qt) {
            // mask loads (overlap with MFMAs)
            const int* mbase = mask
                + (size_t)(b * TSEQ + q0 + w * 32 + qt * 16 + fq * 4) * TSEQ
                + kt * KTL + fr;
            int mv[8][4];
#pragma unroll
            for (int t = 0; t < 8; ++t)
#pragma unroll
                for (int r = 0; r < 4; ++r)
                    mv[t][r] = mbase[r * TSEQ + t * 16];

            // QK^T: S[16 q][128 keys] in 8 C-layout frags
            f32x4 s[8];
#pragma unroll
            for (int t = 0; t < 8; ++t) {
                const bf16x8 kb0 = *(const bf16x8*)&Ks[(t * 16 + fr) * KP + fq * 8];
                const bf16x8 kb1 = *(const bf16x8*)&Ks[(t * 16 + fr) * KP + 32 + fq * 8];
                s[t] = __builtin_amdgcn_mfma_f32_16x16x32_bf16(
                    qa[qt][0], kb0, (f32x4){0.f, 0.f, 0.f, 0.f}, 0, 0, 0);
                s[t] = __builtin_amdgcn_mfma_f32_16x16x32_bf16(
                    qa[qt][1], kb1, s[t], 0, 0, 0);
            }

            // scale + mask
#pragma unroll
            for (int t = 0; t < 8; ++t)
#pragma unroll
                for (int r = 0; r < 4; ++r) {
                    const float v = s[t][r] * 0.03125f;   // 1/sqrt(1024)
                    s[t][r] = (mv[t][r] == 0) ? -1e30f : v;
                }

            // online softmax per row (row = fq*4 + r)
#pragma unroll
            for (int r = 0; r < 4; ++r) {
                float mx = s[0][r];
#pragma unroll
                for (int t = 1; t < 8; ++t) mx = fmaxf(mx, s[t][r]);
#pragma unroll
                for (int off = 8; off > 0; off >>= 1)
                    mx = fmaxf(mx, __shfl_xor(mx, off));
                const float mnew  = fmaxf(mS[qt][r], mx);
                const float alpha = __expf(mS[qt][r] - mnew);
                mS[qt][r] = mnew;
                float ls = 0.f;
#pragma unroll
                for (int t = 0; t < 8; ++t) {
                    const float p = (s[t][r] < -1e29f) ? 0.f : __expf(s[t][r] - mnew);
                    s[t][r] = p;
                    ls += p;
                }
#pragma unroll
                for (int off = 8; off > 0; off >>= 1) ls += __shfl_xor(ls, off);
                lS[qt][r] = lS[qt][r] * alpha + ls;
#pragma unroll
                for (int dt = 0; dt < 4; ++dt) oacc[qt][dt][r] *= alpha;
            }

            // P -> per-wave LDS (C-layout scatter), then A-layout b128 reads.
            // Same-wave DS ops are in-order: qt=1 writes can't pass qt=0 reads.
#pragma unroll
            for (int t = 0; t < 8; ++t)
#pragma unroll
                for (int r = 0; r < 4; ++r)
                    Ps[w][(fq * 4 + r) * PP + t * 16 + fr] = __float2bfloat16(s[t][r]);

            // PV: O[16 q][64 d] += P[16][128] x V[128][64]
#pragma unroll
            for (int kc = 0; kc < 4; ++kc) {
                const bf16x8 pa = *(const bf16x8*)&Ps[w][fr * PP + kc * 32 + fq * 8];
#pragma unroll
                for (int dt = 0; dt < 4; ++dt) {
                    const bf16x8 vb =
                        *(const bf16x8*)&Vs[(dt * 16 + fr) * VP + kc * 32 + fq * 8];
                    oacc[qt][dt] = __builtin_amdgcn_mfma_f32_16x16x32_bf16(
                        pa, vb, oacc[qt][dt], 0, 0, 0);
                }
            }
        }
    }

    // epilogue: normalize, write O (in place over Q; block owns its slice)
#pragma unroll
    for (int qt = 0; qt < 2; ++qt) {
        float inv[4];
#pragma unroll
        for (int r = 0; r < 4; ++r) inv[r] = 1.f / fmaxf(lS[qt][r], 1e-30f);
#pragma unroll
        for (int dt = 0; dt < 4; ++dt)
#pragma unroll
            for (int r = 0; r < 4; ++r)
                O[(size_t)(b * TSEQ + q0 + w * 32 + qt * 16 + fq * 4 + r) * EMBED
                  + h * HD + dt * 16 + fr] =
                    __float2bfloat16(oacc[qt][dt][r] * inv[r]);
    }
}

// ---------------------------------------------------------------------------
// Buffers: ws = [Q | K] bf16 (67 MB). V^T staged in d_out (33.5 MB, dead by
// the final GEMM). Attention writes O over Q; final GEMM Q(ws) -> d_out.
// ---------------------------------------------------------------------------
extern "C" void kernel_launch(void* const* d_in, const int* in_sizes, int n_in,
                              void* d_out, int out_size, void* d_ws, size_t ws_size,
                              hipStream_t stream) {
    const void* X  = d_in[0];
    const int*  Mk = (const int*)d_in[1];
    const void* Wq = d_in[2];
    const void* Wk = d_in[3];
    const void* Wv = d_in[4];
    const void* Wo = d_in[5];
    const void* bo = d_in[6];
    const unsigned int* Xdet = (const unsigned int*)d_in[0];

    const size_t n_elem = (size_t)MROWS * EMBED;
    __hip_bfloat16* Qb  = (__hip_bfloat16*)d_ws;      // ws: Q | K
    __hip_bfloat16* Kb  = Qb + n_elem;
    __hip_bfloat16* Vtb = (__hip_bfloat16*)d_out;     // V^T in d_out

    dim3 blk(256);
    dim3 gg(MROWS / 128, EMBED / 128, 1);
    gemm_flex<<<gg, blk, 0, stream>>>(X, Wq, Qb,  nullptr, Xdet, 1, 0);
    gemm_flex<<<gg, blk, 0, stream>>>(X, Wk, Kb,  nullptr, Xdet, 1, 0);
    gemm_flex<<<gg, blk, 0, stream>>>(X, Wv, Vtb, nullptr, Xdet, 1, 2);

    dim3 ga(TSEQ / QT, NH, NB);                       // 8 x 16 x 16
    attn_mfma<<<ga, blk, 0, stream>>>(Qb, Kb, Vtb, Mk, Qb);

    gemm_flex<<<gg, blk, 0, stream>>>(Qb, Wo, d_out, bo, Xdet, 0, 1);
}

// Round 5
// 1111.394 us; speedup vs baseline: 1.1573x; 1.1573x over previous
//
#include <hip/hip_runtime.h>
#include <hip/hip_bf16.h>

#define EMBED 1024
#define TSEQ  1024
#define NB    16
#define NH    16
#define HD    64
#define MROWS (NB * TSEQ)   // 16384

typedef __bf16 bf16x8 __attribute__((ext_vector_type(8)));
typedef float  f32x4  __attribute__((ext_vector_type(4)));

// float -> bf16 bits, round-to-nearest-even (finite inputs only)
__device__ __forceinline__ unsigned int f2bf_bits(float x) {
    union { float f; unsigned int u; } v; v.f = x;
    unsigned int r = v.u + 0x7FFFu + ((v.u >> 16) & 1u);
    return r >> 16;
}

// async global->LDS, 16 B per lane; LDS dest = wave-uniform base + lane*16
__device__ __forceinline__ void gl2lds16(const void* g, void* lds) {
    __builtin_amdgcn_global_load_lds(
        (const __attribute__((address_space(1))) unsigned int*)g,
        (__attribute__((address_space(3))) unsigned int*)lds, 16, 0, 0);
}

// ---------------------------------------------------------------------------
// Input-dtype sniff (proven R2-R4).
// ---------------------------------------------------------------------------
__device__ __forceinline__ int detect_bf16(const unsigned int* __restrict__ X) {
    __shared__ int s_cnt;
    if (threadIdx.x == 0) s_cnt = 0;
    __syncthreads();
    int c = 0;
    const int base = threadIdx.x * 16;
#pragma unroll
    for (int i = 0; i < 16; ++i) {
        unsigned int e = (X[base + i] >> 7) & 0xFFu;
        c += (e >= 100u && e <= 150u) ? 1 : 0;
    }
    atomicAdd(&s_cnt, c);
    __syncthreads();
    return s_cnt >= 2458;   // 0.6 * 4096
}

__device__ __forceinline__ uint4 load8(const void* __restrict__ p, size_t eoff,
                                       int is_bf16) {
    if (is_bf16) {
        return *(const uint4*)((const __hip_bfloat16*)p + eoff);
    }
    const float* f = (const float*)p + eoff;
    float4 a = *(const float4*)f;
    float4 b = *(const float4*)(f + 4);
    uint4 r;
    r.x = f2bf_bits(a.x) | (f2bf_bits(a.y) << 16);
    r.y = f2bf_bits(a.z) | (f2bf_bits(a.w) << 16);
    r.z = f2bf_bits(b.x) | (f2bf_bits(b.y) << 16);
    r.w = f2bf_bits(b.z) | (f2bf_bits(b.w) << 16);
    return r;
}

// ---------------------------------------------------------------------------
// Mask bit-plane: pm[((b*8+kt)*16+fr)*1024 + q] byte holds bits t=0..7 for
// key = kt*128 + t*16 + fr of query q. 2 MB total -> L2-resident in attn.
// Thread = (b*8+kt)*1024 + q: reads 128 consecutive ints, writes 16 bytes
// (coalesced across lanes since consecutive lanes = consecutive q).
// ---------------------------------------------------------------------------
__global__ __launch_bounds__(256) void pack_mask(
    const int* __restrict__ mask, unsigned char* __restrict__ pm)
{
    const int t  = blockIdx.x * 256 + threadIdx.x;  // 0..131071
    const int q  = t & 1023;
    const int bk = t >> 10;                          // b*8 + kt
    const int b  = bk >> 3, kt = bk & 7;
    const int* row = mask + ((size_t)b * 1024 + q) * 1024 + kt * 128;
    unsigned int bits[16];
#pragma unroll
    for (int fr = 0; fr < 16; ++fr) bits[fr] = 0u;
#pragma unroll
    for (int tt = 0; tt < 8; ++tt)
#pragma unroll
        for (int fr = 0; fr < 16; ++fr)
            bits[fr] |= (row[tt * 16 + fr] != 0 ? 1u : 0u) << tt;
#pragma unroll
    for (int fr = 0; fr < 16; ++fr)
        pm[((size_t)(bk * 16 + fr)) * 1024 + q] = (unsigned char)bits[fr];
}

// ---------------------------------------------------------------------------
// C[m][n] = sum_k A[m][k] * W[n][k]  (+ bias[n])
// Fast path (all-bf16): BK=64, global_load_lds width-16 into unpadded
// [128][64] tiles (m97-pattern frag reads), 2 barriers per 64-wide K-step
// (half of R4's drain count). Flex path (any f32): R3 structure, BK=32.
// out_mode: 0 = bf16 C; 1 = detected-dtype C; 2 = bf16 Vt[b][h][d][t].
// ---------------------------------------------------------------------------
#define LDK 40   // flex-path LDS row stride

__global__ __launch_bounds__(256) void gemm_flex(
    const void* __restrict__ A,
    const void* __restrict__ W,
    void* __restrict__ C,
    const void* __restrict__ bias,
    const unsigned int* __restrict__ Xdet,
    int a_flex, int out_mode)
{
    const int isbf = detect_bf16(Xdet);

    __shared__ __hip_bfloat16 As[128 * 64];   // 16 KB (flex uses stride-40 slice)
    __shared__ __hip_bfloat16 Bs[128 * 64];

    const int tid  = threadIdx.x;
    const int lane = tid & 63;
    const int w    = tid >> 6;
    const int wm   = w & 1;
    const int wn   = w >> 1;
    const int m0   = blockIdx.x * 128;
    const int n0   = blockIdx.y * 128;

    f32x4 acc[4][4];
#pragma unroll
    for (int i = 0; i < 4; ++i)
#pragma unroll
        for (int j = 0; j < 4; ++j)
            acc[i][j] = (f32x4){0.f, 0.f, 0.f, 0.f};

    const int fr = lane & 15;
    const int fq = lane >> 4;

    if (isbf) {
        // ---- fast path: BK=64, gl2lds ----
        // tile = [128 rows][64 cols] bf16 = 16 KB = 1024 chunks of 16 B;
        // chunk f = i*256 + tid: row = f>>3, col-slot = f&7.
        const int row  = tid >> 3;          // rows covered per i: +32 each
        const int slot = tid & 7;
        const __hip_bfloat16* gA =
            (const __hip_bfloat16*)A + (size_t)(m0 + row) * EMBED + slot * 8;
        const __hip_bfloat16* gB =
            (const __hip_bfloat16*)W + (size_t)(n0 + row) * EMBED + slot * 8;
        __hip_bfloat16* lA = &As[(size_t)tid * 8];   // + i*2048 elements
        __hip_bfloat16* lB = &Bs[(size_t)tid * 8];

        for (int k0 = 0; k0 < EMBED; k0 += 64) {
            __syncthreads();   // prev iter's frag reads done before DMA overwrite
#pragma unroll
            for (int i = 0; i < 4; ++i) {
                gl2lds16(gA + k0 + (size_t)(i * 32) * EMBED, lA + i * 2048);
                gl2lds16(gB + k0 + (size_t)(i * 32) * EMBED, lB + i * 2048);
            }
            __syncthreads();   // drains vmcnt -> tiles resident

#pragma unroll
            for (int kc = 0; kc < 2; ++kc) {
                bf16x8 af[4], bfr[4];
#pragma unroll
                for (int i = 0; i < 4; ++i) {
                    af[i]  = *(const bf16x8*)
                        &As[(wm * 64 + i * 16 + fr) * 64 + kc * 32 + fq * 8];
                    bfr[i] = *(const bf16x8*)
                        &Bs[(wn * 64 + i * 16 + fr) * 64 + kc * 32 + fq * 8];
                }
#pragma unroll
                for (int i = 0; i < 4; ++i)
#pragma unroll
                    for (int j = 0; j < 4; ++j)
                        acc[i][j] = __builtin_amdgcn_mfma_f32_16x16x32_bf16(
                            af[i], bfr[j], acc[i][j], 0, 0, 0);
            }
        }
    } else {
        // ---- flex path (any-f32 operands; R3 structure, BK=32) ----
        const int a_bf = a_flex ? 0 : 1;
        const int r0 = tid >> 2;
        const int c0 = (tid & 3) * 8;
        for (int k0 = 0; k0 < EMBED; k0 += 32) {
            uint4 ra0 = load8(A, (size_t)(m0 + r0)      * EMBED + c0 + k0, a_bf);
            uint4 ra1 = load8(A, (size_t)(m0 + r0 + 64) * EMBED + c0 + k0, a_bf);
            uint4 rb0 = load8(W, (size_t)(n0 + r0)      * EMBED + c0 + k0, 0);
            uint4 rb1 = load8(W, (size_t)(n0 + r0 + 64) * EMBED + c0 + k0, 0);
            __syncthreads();
            *(uint4*)&As[r0 * LDK + c0]        = ra0;
            *(uint4*)&As[(r0 + 64) * LDK + c0] = ra1;
            *(uint4*)&Bs[r0 * LDK + c0]        = rb0;
            *(uint4*)&Bs[(r0 + 64) * LDK + c0] = rb1;
            __syncthreads();

            bf16x8 af[4], bfr[4];
#pragma unroll
            for (int i = 0; i < 4; ++i) {
                af[i]  = *(const bf16x8*)&As[(wm * 64 + i * 16 + fr) * LDK + fq * 8];
                bfr[i] = *(const bf16x8*)&Bs[(wn * 64 + i * 16 + fr) * LDK + fq * 8];
            }
#pragma unroll
            for (int i = 0; i < 4; ++i)
#pragma unroll
                for (int j = 0; j < 4; ++j)
                    acc[i][j] = __builtin_amdgcn_mfma_f32_16x16x32_bf16(
                        af[i], bfr[j], acc[i][j], 0, 0, 0);
        }
    }

    float bv[4] = {0.f, 0.f, 0.f, 0.f};
    if (bias != nullptr) {
#pragma unroll
        for (int j = 0; j < 4; ++j) {
            const int idx = n0 + wn * 64 + j * 16 + fr;
            bv[j] = isbf ? __bfloat162float(((const __hip_bfloat16*)bias)[idx])
                         : ((const float*)bias)[idx];
        }
    }

    if (out_mode == 2) {
        // Vt[b][h][d][t]: C-layout regs r=0..3 are 4 consecutive t -> uint2
#pragma unroll
        for (int i = 0; i < 4; ++i) {
            const int row = m0 + wm * 64 + i * 16 + fq * 4;   // token (base)
            const int bb = row >> 10, tt = row & 1023;
#pragma unroll
            for (int j = 0; j < 4; ++j) {
                const int col = n0 + wn * 64 + j * 16 + fr;   // channel
                const int hh = col >> 6, dd = col & 63;
                uint2 st;
                st.x = f2bf_bits(acc[i][j][0]) | (f2bf_bits(acc[i][j][1]) << 16);
                st.y = f2bf_bits(acc[i][j][2]) | (f2bf_bits(acc[i][j][3]) << 16);
                *(uint2*)&((__hip_bfloat16*)C)[
                    (((size_t)(bb * NH + hh) * HD + dd) * TSEQ) + tt] = st;
            }
        }
        return;
    }

    const int c_bf = (out_mode == 1) ? isbf : 1;
#pragma unroll
    for (int i = 0; i < 4; ++i) {
        const int row = m0 + wm * 64 + i * 16 + fq * 4;
#pragma unroll
        for (int j = 0; j < 4; ++j) {
            const int col = n0 + wn * 64 + j * 16 + fr;
#pragma unroll
            for (int r = 0; r < 4; ++r) {
                const size_t off = (size_t)(row + r) * EMBED + col;
                const float v = acc[i][j][r] + bv[j];
                if (c_bf) ((__hip_bfloat16*)C)[off] = __float2bfloat16(v);
                else      ((float*)C)[off] = v;
            }
        }
    }
}

// ---------------------------------------------------------------------------
// MFMA flash attention. 256 thr (4 waves) x 128 queries (32 q/wave as two
// 16-q sub-tiles); 8 KV-tiles of 128 keys. __launch_bounds__(256,2) -> VGPR
// cap 256: the R4 spill (WRITE_SIZE 952 MB) is structurally impossible.
// K/V staged by gl2lds into unpadded tiles; K B-frags shared across both
// sub-tiles (read once per kt). Mask from the 2 MB bit-plane: 1 u32 per
// (qt,kt) per lane. P transposes through per-wave LDS. O written over Q.
// ---------------------------------------------------------------------------
#define QT  128
#define KTL 128
#define PP  136   // Ps pitch: +8 pad -> conflict-light scalar writes

__global__ __launch_bounds__(256, 2) void attn_mfma(
    const __hip_bfloat16* __restrict__ Q,
    const __hip_bfloat16* __restrict__ K,
    const __hip_bfloat16* __restrict__ Vt,
    const unsigned char* __restrict__ pm,
    __hip_bfloat16* __restrict__ O)
{
    __shared__ __hip_bfloat16 Ks[KTL * HD];     // [key][d]   16 KB
    __shared__ __hip_bfloat16 Vs[HD * KTL];     // [d][key]   16 KB
    __shared__ __hip_bfloat16 Ps[4][16 * PP];   // 17.4 KB

    const int tid  = threadIdx.x;
    const int lane = tid & 63;
    const int w    = tid >> 6;
    const int fr   = lane & 15;
    const int fq   = lane >> 4;
    const int qb = blockIdx.x, h = blockIdx.y, b = blockIdx.z;
    const int q0 = qb * QT;

    // Q A-frags for both 16-q sub-tiles: A[m=fr][k=fq*8+j], k-chunks 0/32
    bf16x8 qa[2][2];
#pragma unroll
    for (int qt = 0; qt < 2; ++qt) {
        const __hip_bfloat16* qptr =
            Q + (size_t)(b * TSEQ + q0 + w * 32 + qt * 16 + fr) * EMBED
              + h * HD + fq * 8;
        qa[qt][0] = *(const bf16x8*)qptr;
        qa[qt][1] = *(const bf16x8*)(qptr + 32);
    }

    float mS[2][4], lS[2][4];
    f32x4 oacc[2][4];
#pragma unroll
    for (int qt = 0; qt < 2; ++qt)
#pragma unroll
        for (int r = 0; r < 4; ++r) {
            mS[qt][r] = -1e30f; lS[qt][r] = 0.f;
            oacc[qt][r] = (f32x4){0.f, 0.f, 0.f, 0.f};
        }

    // staging geometry (chunk f = i*256 + tid)
    const int krow = tid >> 3, kcol = (tid & 7) * 8;    // K: +32 rows per i
    const int vrow = tid >> 4, vcol = (tid & 15) * 8;   // V: +16 rows per i
    const __hip_bfloat16* gK =
        K + (size_t)(b * TSEQ + krow) * EMBED + h * HD + kcol;
    const __hip_bfloat16* gV =
        Vt + ((size_t)(b * NH + h) * HD + vrow) * TSEQ + vcol;
    const unsigned char* pmb =
        pm + ((size_t)(b * 8) * 16 + fr) * 1024 + q0 + w * 32 + fq * 4;

    for (int kt = 0; kt < TSEQ / KTL; ++kt) {
        __syncthreads();   // prev iter's frag reads done before DMA overwrite
#pragma unroll
        for (int i = 0; i < 4; ++i) {
            gl2lds16(gK + (size_t)(kt * KTL + i * 32) * EMBED,
                     &Ks[(size_t)tid * 8 + i * 2048]);
            gl2lds16(gV + (size_t)(i * 16) * TSEQ + kt * KTL,
                     &Vs[(size_t)tid * 8 + i * 2048]);
        }
        // mask words (drained by the same barrier)
        const unsigned int mb0 = *(const unsigned int*)(pmb + (size_t)kt * 16384);
        const unsigned int mb1 = *(const unsigned int*)(pmb + (size_t)kt * 16384 + 16);
        __syncthreads();   // vmcnt(0) -> tiles resident

        // QK^T for both sub-tiles, K-frags read once
        f32x4 s0[8], s1[8];
#pragma unroll
        for (int t = 0; t < 8; ++t) {
            const bf16x8 kb0 = *(const bf16x8*)&Ks[(t * 16 + fr) * 64 + fq * 8];
            const bf16x8 kb1 = *(const bf16x8*)&Ks[(t * 16 + fr) * 64 + 32 + fq * 8];
            s0[t] = __builtin_amdgcn_mfma_f32_16x16x32_bf16(
                qa[0][0], kb0, (f32x4){0.f, 0.f, 0.f, 0.f}, 0, 0, 0);
            s0[t] = __builtin_amdgcn_mfma_f32_16x16x32_bf16(qa[0][1], kb1, s0[t], 0, 0, 0);
            s1[t] = __builtin_amdgcn_mfma_f32_16x16x32_bf16(
                qa[1][0], kb0, (f32x4){0.f, 0.f, 0.f, 0.f}, 0, 0, 0);
            s1[t] = __builtin_amdgcn_mfma_f32_16x16x32_bf16(qa[1][1], kb1, s1[t], 0, 0, 0);
        }

#pragma unroll 1
        for (int qt = 0; qt < 2; ++qt) {
            f32x4* s = qt ? s1 : s0;
            const unsigned int mb = qt ? mb1 : mb0;

            // scale + mask from bit-plane: bit (8*r+t) of mb
#pragma unroll
            for (int t = 0; t < 8; ++t)
#pragma unroll
                for (int r = 0; r < 4; ++r) {
                    const float v = s[t][r] * 0.03125f;   // 1/sqrt(1024)
                    s[t][r] = ((mb >> (8 * r + t)) & 1u) ? v : -1e30f;
                }

            // online softmax per row (row = fq*4 + r)
#pragma unroll
            for (int r = 0; r < 4; ++r) {
                float mx = s[0][r];
#pragma unroll
                for (int t = 1; t < 8; ++t) mx = fmaxf(mx, s[t][r]);
#pragma unroll
                for (int off = 8; off > 0; off >>= 1)
                    mx = fmaxf(mx, __shfl_xor(mx, off));
                const float mnew  = fmaxf(mS[qt][r], mx);
                const float alpha = __expf(mS[qt][r] - mnew);
                mS[qt][r] = mnew;
                float ls = 0.f;
#pragma unroll
                for (int t = 0; t < 8; ++t) {
                    const float p = (s[t][r] < -1e29f) ? 0.f : __expf(s[t][r] - mnew);
                    s[t][r] = p;
                    ls += p;
                }
#pragma unroll
                for (int off = 8; off > 0; off >>= 1) ls += __shfl_xor(ls, off);
                lS[qt][r] = lS[qt][r] * alpha + ls;
#pragma unroll
                for (int dt = 0; dt < 4; ++dt) oacc[qt][dt][r] *= alpha;
            }

            // P -> per-wave LDS (C-layout scatter), then A-layout b128 reads.
            // Same-wave DS ops are in-order: qt=1 writes can't pass qt=0 reads.
#pragma unroll
            for (int t = 0; t < 8; ++t)
#pragma unroll
                for (int r = 0; r < 4; ++r)
                    Ps[w][(fq * 4 + r) * PP + t * 16 + fr] = __float2bfloat16(s[t][r]);

            // PV: O[16 q][64 d] += P[16][128] x V[128][64]
#pragma unroll
            for (int kc = 0; kc < 4; ++kc) {
                const bf16x8 pa = *(const bf16x8*)&Ps[w][fr * PP + kc * 32 + fq * 8];
#pragma unroll
                for (int dt = 0; dt < 4; ++dt) {
                    const bf16x8 vb =
                        *(const bf16x8*)&Vs[(dt * 16 + fr) * KTL + kc * 32 + fq * 8];
                    oacc[qt][dt] = __builtin_amdgcn_mfma_f32_16x16x32_bf16(
                        pa, vb, oacc[qt][dt], 0, 0, 0);
                }
            }
        }
    }

    // epilogue: normalize, write O (in place over Q; block owns its slice)
#pragma unroll
    for (int qt = 0; qt < 2; ++qt) {
        float inv[4];
#pragma unroll
        for (int r = 0; r < 4; ++r) inv[r] = 1.f / fmaxf(lS[qt][r], 1e-30f);
#pragma unroll
        for (int dt = 0; dt < 4; ++dt)
#pragma unroll
            for (int r = 0; r < 4; ++r)
                O[(size_t)(b * TSEQ + q0 + w * 32 + qt * 16 + fq * 4 + r) * EMBED
                  + h * HD + dt * 16 + fr] =
                    __float2bfloat16(oacc[qt][dt][r] * inv[r]);
    }
}

// ---------------------------------------------------------------------------
// Buffers: ws = [Q | K | pm] (67 MB + 2 MB). V^T staged in d_out (dead by
// the final GEMM). Attention writes O over Q; final GEMM Q(ws) -> d_out.
// ---------------------------------------------------------------------------
extern "C" void kernel_launch(void* const* d_in, const int* in_sizes, int n_in,
                              void* d_out, int out_size, void* d_ws, size_t ws_size,
                              hipStream_t stream) {
    const void* X  = d_in[0];
    const int*  Mk = (const int*)d_in[1];
    const void* Wq = d_in[2];
    const void* Wk = d_in[3];
    const void* Wv = d_in[4];
    const void* Wo = d_in[5];
    const void* bo = d_in[6];
    const unsigned int* Xdet = (const unsigned int*)d_in[0];

    const size_t n_elem = (size_t)MROWS * EMBED;
    __hip_bfloat16* Qb  = (__hip_bfloat16*)d_ws;      // ws: Q | K | pm
    __hip_bfloat16* Kb  = Qb + n_elem;
    unsigned char*  pm  = (unsigned char*)(Kb + n_elem);   // 2 MB bit-plane
    __hip_bfloat16* Vtb = (__hip_bfloat16*)d_out;     // V^T in d_out

    dim3 blk(256);
    pack_mask<<<dim3(512), blk, 0, stream>>>(Mk, pm);

    dim3 gg(MROWS / 128, EMBED / 128, 1);
    gemm_flex<<<gg, blk, 0, stream>>>(X, Wq, Qb,  nullptr, Xdet, 1, 0);
    gemm_flex<<<gg, blk, 0, stream>>>(X, Wk, Kb,  nullptr, Xdet, 1, 0);
    gemm_flex<<<gg, blk, 0, stream>>>(X, Wv, Vtb, nullptr, Xdet, 1, 2);

    dim3 ga(TSEQ / QT, NH, NB);                       // 8 x 16 x 16
    attn_mfma<<<ga, blk, 0, stream>>>(Qb, Kb, Vtb, pm, Qb);

    gemm_flex<<<gg, blk, 0, stream>>>(Qb, Wo, d_out, bo, Xdet, 0, 1);
}